// Round 18
// baseline (321.720 us; speedup 1.0000x reference)
//
#include <hip/hip_runtime.h>
#include <stdint.h>

#define CC 32
#define TOPK 1024
#define FC0 256
#define HL 8192   // half-segment length

// compare-exchange via shfl_xor: partner lane = lane^s (s <= 32, same wave).
__device__ __forceinline__ uint64_t cex(uint64_t v, int s, bool up, int t)
{
    uint64_t o = (uint64_t)__shfl_xor((unsigned long long)v, s, 64);
    bool left = ((t & s) == 0);
    uint64_t mn = v < o ? v : o;
    uint64_t mx = v < o ? o : v;
    return (left == up) ? mn : mx;
}

// ------------- Kernel 1: f32 att keys (r15 exact; measured 38.7 us = BW floor)
__global__ __launch_bounds__(256)
void k_att(const float* __restrict__ x,
           const float* __restrict__ w_att, const float* __restrict__ b_att,
           uint32_t* __restrict__ key, int N)
{
    __shared__ float tile[256][CC + 1];
    const int t = threadIdx.x;
    const size_t base = (size_t)blockIdx.x * 256;
    const float4* xv = (const float4*)(x + base * CC);
    #pragma unroll
    for (int i = 0; i < 8; ++i) {
        int e = i * 256 + t;
        float4 v = xv[e];
        int r = e >> 3, c4 = (e & 7) * 4;
        tile[r][c4 + 0] = v.x; tile[r][c4 + 1] = v.y;
        tile[r][c4 + 2] = v.z; tile[r][c4 + 3] = v.w;
    }
    __syncthreads();
    float p[8];
    #pragma unroll
    for (int j = 0; j < 8; ++j) {
        float pj = __fmul_rn(tile[t][j], w_att[j]);
        pj = __fmaf_rn(tile[t][8 + j],  w_att[8 + j],  pj);
        pj = __fmaf_rn(tile[t][16 + j], w_att[16 + j], pj);
        pj = __fmaf_rn(tile[t][24 + j], w_att[24 + j], pj);
        p[j] = pj;
    }
    float q0 = __fadd_rn(p[0], p[1]);
    float q1 = __fadd_rn(p[2], p[3]);
    float q2 = __fadd_rn(p[4], p[5]);
    float q3 = __fadd_rn(p[6], p[7]);
    float dot = __fadd_rn(__fadd_rn(q0, q1), __fadd_rn(q2, q3));
    float v = __fadd_rn(dot, b_att[0]);
    uint32_t bits = __float_as_uint(v);
    key[base + t] = (bits & 0x80000000u) ? ~bits : (bits | 0x80000000u);
}

// ---------- Kernel 2: half-segment top-1024 (r15 exact; measured 21.0 us) ----
__global__ __launch_bounds__(1024)
void k_halfsel(const uint32_t* __restrict__ key, uint64_t* __restrict__ cand)
{
    __shared__ uint32_t kv[HL];           // 32 KB
    __shared__ uint64_t cv[2048];         // 16 KB
    __shared__ uint32_t hist[257];        // hist[256]=0 sentinel
    __shared__ uint32_t s_prefix, s_k, s_cnt;
    const int t = threadIdx.x;
    const int b = blockIdx.x;
    const int lane = t & 63;
    const uint32_t halfbase = (uint32_t)(b & 1) * HL;

    {   // vectorized load: 8192 keys = 2048 uint4
        const uint4* ks = (const uint4*)(key + (size_t)b * HL);
        uint4 a = ks[t], c = ks[t + 1024];
        *(uint4*)&kv[t * 4] = a;
        *(uint4*)&kv[(t + 1024) * 4] = c;
    }
    if (t == 0) { s_prefix = 0; s_k = TOPK; s_cnt = 0; }
    __syncthreads();

    #pragma unroll
    for (int round = 0; round < 2; ++round) {
        if (t < 257) hist[t] = 0;
        __syncthreads();
        const uint32_t pref = s_prefix;
        const uint32_t k = s_k;
        for (int i = t; i < HL; i += 1024) {
            uint32_t u = kv[i];
            if (round == 0) atomicAdd(&hist[u >> 24], 1u);
            else if ((u >> 24) == pref) atomicAdd(&hist[(u >> 16) & 255u], 1u);
        }
        __syncthreads();
        if (t < 64) {
            int l = t;
            uint32_t h0 = hist[4*l], h1 = hist[4*l+1], h2 = hist[4*l+2], h3 = hist[4*l+3];
            uint32_t s3 = h3, s2 = h2 + s3, s1 = h1 + s2, s0 = h0 + s1;
            uint32_t tot = s0, run = tot;
            #pragma unroll
            for (int off = 1; off < 64; off <<= 1) {
                int src = l + off < 64 ? l + off : 63;
                uint32_t o = __shfl(run, src, 64);
                if (l + off < 64) run += o;
            }
            uint32_t esuf = run - tot;
            hist[4*l]   = s0 + esuf; hist[4*l+1] = s1 + esuf;
            hist[4*l+2] = s2 + esuf; hist[4*l+3] = s3 + esuf;
        }
        __syncthreads();
        if (t < 256) {
            uint32_t st = hist[t], sn = hist[t + 1];
            if (st >= k && sn < k) {
                s_prefix = (pref << 8) | (uint32_t)t;
                s_k = k - sn;
            }
        }
        __syncthreads();
    }
    const uint32_t T = s_prefix << 16;

    for (int i = t; i < HL; i += 1024) {
        bool q = kv[i] >= T;
        unsigned long long m = __ballot(q);
        uint32_t base = 0;
        if (lane == 0 && m)
            base = atomicAdd(&s_cnt, (uint32_t)__popcll(m));
        base = __shfl(base, 0);
        if (q) {
            uint32_t pos = base + (uint32_t)__popcll(m & ((1ULL << lane) - 1ULL));
            if (pos < 2048)
                cv[pos] = ((uint64_t)kv[i] << 32)
                        | (uint64_t)(uint32_t)(~(halfbase + (uint32_t)i));
        }
    }
    __syncthreads();
    const uint32_t mm = s_cnt < 2048u ? s_cnt : 2048u;
    for (int i = t; i < 2048; i += 1024)
        if ((uint32_t)i >= mm) cv[i] = 0ULL;
    __syncthreads();

    {   // Phase A: sizes 2..64 in registers via shfl
        uint64_t r0 = cv[t], r1 = cv[t + 1024];
        #pragma unroll
        for (int size = 2; size <= 64; size <<= 1) {
            bool up = ((t & size) == 0);
            #pragma unroll
            for (int s = size >> 1; s > 0; s >>= 1) {
                r0 = cex(r0, s, up, t);
                r1 = cex(r1, s, up, t);
            }
        }
        cv[t] = r0; cv[t + 1024] = r1;
    }
    #pragma unroll
    for (int size = 128; size <= 2048; size <<= 1) {
        for (int s = size >> 1; s >= 64; s >>= 1) {
            __syncthreads();
            int i = ((t & ~(s - 1)) << 1) | (t & (s - 1));
            int j = i | s;
            uint64_t va = cv[i], vb = cv[j];
            bool up = ((i & size) == 0);
            if (up ? (va > vb) : (va < vb)) { cv[i] = vb; cv[j] = va; }
        }
        __syncthreads();
        {
            uint64_t a0 = cv[t], a1 = cv[t + 1024];
            bool up0, up1;
            if (size <= 512)      { up0 = ((t & size) == 0); up1 = up0; }
            else if (size == 1024){ up0 = true;  up1 = false; }
            else                  { up0 = true;  up1 = true;  }
            #pragma unroll
            for (int s = 32; s > 0; s >>= 1) {
                a0 = cex(a0, s, up0, t);
                a1 = cex(a1, s, up1, t);
            }
            cv[t] = a0; cv[t + 1024] = a1;
        }
        __syncthreads();
    }
    cand[(size_t)b * TOPK + t] = cv[2047 - t];   // half top-1024, desc
}

// ---------- Kernel 3: merge two half top-1024 lists (r15 exact) --------------
// MEASUREMENT r18: x6.
__global__ __launch_bounds__(1024)
void k_merge(const uint64_t* __restrict__ cand, int* __restrict__ idx_out)
{
    __shared__ uint64_t cv[2048];
    const int t = threadIdx.x;
    const int seg = blockIdx.x;
    cv[t]        = cand[(size_t)(seg * 2) * TOPK + t];
    cv[1024 + t] = cand[(size_t)(seg * 2 + 1) * TOPK + (1023 - t)];
    __syncthreads();
    for (int s = 1024; s >= 1; s >>= 1) {
        int i = ((t & ~(s - 1)) << 1) | (t & (s - 1));
        int j = i | s;
        uint64_t va = cv[i], vb = cv[j];
        if (va < vb) { cv[i] = vb; cv[j] = va; }   // descending
        __syncthreads();
    }
    idx_out[(size_t)seg * TOPK + t] = (int)(~(uint32_t)cv[t]);
}

// ---------------- Kernel 4: gather + K-split GEMM partials (r15 exact) -------
// MEASUREMENT r18: x6.
#define FT 64
#define KCI 32
#define NKC 128
#define KCHUNK 256   // = TOPK*CC / NKC

__global__ __launch_bounds__(256)
void k_fc(const float* __restrict__ x, const int* __restrict__ idx,
          const float* __restrict__ W, float* __restrict__ part, int L)
{
    __shared__ float flT[KCI][128];   // [k][b] 16 KB
    __shared__ float wT[KCI][FT];     // [k][f]  8 KB
    const int t = threadIdx.x;
    const int kc = blockIdx.x;
    const int fb = blockIdx.y * FT;
    const int tb = t >> 4, tf = t & 15;   // 16x16 grid: 8b x 4f per thread
    float acc[8][4];
    #pragma unroll
    for (int i = 0; i < 8; ++i)
        #pragma unroll
        for (int j = 0; j < 4; ++j) acc[i][j] = 0.f;

    const int b_ld = t >> 1, half = t & 1;
    for (int sub = 0; sub < KCHUNK / KCI; ++sub) {
        const int kbase = kc * KCHUNK + sub * KCI;
        const int t_idx = kbase >> 5;    // KCI == CC: one topk position per sub
        {   // stage gathered x rows: flT[c][b]
            int row = idx[b_ld * TOPK + t_idx];
            row = row < 0 ? 0 : (row >= L ? L - 1 : row);
            const float* src = x + ((size_t)b_ld * L + row) * CC + half * 16;
            #pragma unroll
            for (int q = 0; q < 4; ++q) {
                float4 v = ((const float4*)src)[q];
                int c0 = half * 16 + q * 4;
                flT[c0 + 0][b_ld] = v.x; flT[c0 + 1][b_ld] = v.y;
                flT[c0 + 2][b_ld] = v.z; flT[c0 + 3][b_ld] = v.w;
            }
        }
        {   // stage W transposed: wT[k][f], 64 f x 32 k
            #pragma unroll
            for (int i2 = 0; i2 < 2; ++i2) {
                int e = t + i2 * 256;
                int fl = e >> 3, u = e & 7;
                const float4 v = *(const float4*)(W + (size_t)(fb + fl) * (TOPK * CC) + kbase + u * 4);
                wT[u * 4 + 0][fl] = v.x; wT[u * 4 + 1][fl] = v.y;
                wT[u * 4 + 2][fl] = v.z; wT[u * 4 + 3][fl] = v.w;
            }
        }
        __syncthreads();
        #pragma unroll
        for (int kk = 0; kk < KCI; ++kk) {
            float bb[8], ww[4];
            *(float4*)&bb[0] = *(const float4*)&flT[kk][tb * 8];
            *(float4*)&bb[4] = *(const float4*)&flT[kk][tb * 8 + 4];
            *(float4*)&ww[0] = *(const float4*)&wT[kk][tf * 4];
            #pragma unroll
            for (int i = 0; i < 8; ++i)
                #pragma unroll
                for (int j = 0; j < 4; ++j)
                    acc[i][j] = fmaf(bb[i], ww[j], acc[i][j]);
        }
        __syncthreads();
    }
    float* pbase = part + ((size_t)kc * 128) * 256 + fb + tf * 4;
    #pragma unroll
    for (int i = 0; i < 8; ++i) {
        float* dst = pbase + (size_t)(tb * 8 + i) * 256;
        ((float4*)dst)[0] = make_float4(acc[i][0], acc[i][1], acc[i][2], acc[i][3]);
    }
}

// ---------------- Kernel 5: reduce partials + bias + BN2 + L2 norm (r15 exact)
// MEASUREMENT r18: x6.
__global__ __launch_bounds__(256)
void k_post(const float* __restrict__ part, const float* __restrict__ b_fc,
            const float* __restrict__ g2, const float* __restrict__ be2,
            const float* __restrict__ rm2, const float* __restrict__ rv2,
            float* __restrict__ out)
{
    __shared__ float red[256];
    const int b = blockIdx.x, f = threadIdx.x;
    float s = 0.f;
    #pragma unroll 8
    for (int kc = 0; kc < NKC; ++kc)
        s += part[((size_t)kc * 128 + b) * 256 + f];
    s += b_fc[f];
    float o = (s - rm2[f]) * (g2[f] / sqrtf(rv2[f] + 1e-5f)) + be2[f];
    red[f] = o * o;
    __syncthreads();
    for (int st = 128; st > 0; st >>= 1) {
        if (f < st) red[f] += red[f + st];
        __syncthreads();
    }
    float nrm = fmaxf(sqrtf(red[0]), 1e-12f);
    out[(size_t)b * 256 + f] = o / nrm;
}

extern "C" void kernel_launch(void* const* d_in, const int* in_sizes, int n_in,
                              void* d_out, int out_size, void* d_ws, size_t ws_size,
                              hipStream_t stream)
{
    const float* x     = (const float*)d_in[0];
    const float* w_att = (const float*)d_in[2];
    const float* b_att = (const float*)d_in[3];
    const float* W_fc  = (const float*)d_in[8];
    const float* b_fc  = (const float*)d_in[9];
    const float* g2    = (const float*)d_in[10];
    const float* be2   = (const float*)d_in[11];
    const float* rm2   = (const float*)d_in[12];
    const float* rv2   = (const float*)d_in[13];

    const int N = in_sizes[0] / CC;   // 2097152
    const int B = in_sizes[1];        // 128
    const int L = N / B;              // 16384

    // workspace layout
    const size_t off_key  = 0;                                   // 8 MB
    const size_t off_cand = off_key + (size_t)N * 4;             // 2 MB
    const size_t off_idx  = off_cand + (size_t)2 * B * TOPK * 8; // 512 KB
    const size_t off_part = off_idx + (size_t)B * TOPK * 4;      // 16 MB

    uint8_t* ws = (uint8_t*)d_ws;
    uint32_t* key  = (uint32_t*)(ws + off_key);
    uint64_t* cand = (uint64_t*)(ws + off_cand);
    int* idx       = (int*)(ws + off_idx);
    float* part    = (float*)(ws + off_part);

    k_att<<<N / 256, 256, 0, stream>>>(x, w_att, b_att, key, N);
    k_halfsel<<<2 * B, 1024, 0, stream>>>(key, cand);
    // MEASUREMENT: x6 merge, fc, post (all idempotent).
    // S = F+M+P = (dur_us - 115.1)/5 ; gaps = 115.1 - 38.7 - 21.0 - S.
    for (int rep = 0; rep < 6; ++rep)
        k_merge<<<B, 1024, 0, stream>>>(cand, idx);
    dim3 g3(NKC, FC0 / FT);
    for (int rep = 0; rep < 6; ++rep)
        k_fc<<<g3, 256, 0, stream>>>(x, idx, W_fc, part, L);
    for (int rep = 0; rep < 6; ++rep)
        k_post<<<B, 256, 0, stream>>>(part, b_fc, g2, be2, rm2, rv2, (float*)d_out);
}

// Round 19
// 122.689 us; speedup vs baseline: 2.6222x; 2.6222x over previous
//
#include <hip/hip_runtime.h>
#include <stdint.h>

#define CC 32
#define TOPK 1024
#define FC0 256
#define HL 8192   // half-segment length

// compare-exchange via shfl_xor: partner lane = lane^s (s <= 32, same wave).
__device__ __forceinline__ uint64_t cex(uint64_t v, int s, bool up, int t)
{
    uint64_t o = (uint64_t)__shfl_xor((unsigned long long)v, s, 64);
    bool left = ((t & s) == 0);
    uint64_t mn = v < o ? v : o;
    uint64_t mx = v < o ? o : v;
    return (left == up) ? mn : mx;
}

// ------------- Kernel 1: f32 att keys (r15 exact; measured 38.7 us = BW floor)
__global__ __launch_bounds__(256)
void k_att(const float* __restrict__ x,
           const float* __restrict__ w_att, const float* __restrict__ b_att,
           uint32_t* __restrict__ key, int N)
{
    __shared__ float tile[256][CC + 1];
    const int t = threadIdx.x;
    const size_t base = (size_t)blockIdx.x * 256;
    const float4* xv = (const float4*)(x + base * CC);
    #pragma unroll
    for (int i = 0; i < 8; ++i) {
        int e = i * 256 + t;
        float4 v = xv[e];
        int r = e >> 3, c4 = (e & 7) * 4;
        tile[r][c4 + 0] = v.x; tile[r][c4 + 1] = v.y;
        tile[r][c4 + 2] = v.z; tile[r][c4 + 3] = v.w;
    }
    __syncthreads();
    float p[8];
    #pragma unroll
    for (int j = 0; j < 8; ++j) {
        float pj = __fmul_rn(tile[t][j], w_att[j]);
        pj = __fmaf_rn(tile[t][8 + j],  w_att[8 + j],  pj);
        pj = __fmaf_rn(tile[t][16 + j], w_att[16 + j], pj);
        pj = __fmaf_rn(tile[t][24 + j], w_att[24 + j], pj);
        p[j] = pj;
    }
    float q0 = __fadd_rn(p[0], p[1]);
    float q1 = __fadd_rn(p[2], p[3]);
    float q2 = __fadd_rn(p[4], p[5]);
    float q3 = __fadd_rn(p[6], p[7]);
    float dot = __fadd_rn(__fadd_rn(q0, q1), __fadd_rn(q2, q3));
    float v = __fadd_rn(dot, b_att[0]);
    uint32_t bits = __float_as_uint(v);
    key[base + t] = (bits & 0x80000000u) ? ~bits : (bits | 0x80000000u);
}

// ---------- Kernel 2: half-segment top-1024, keys in REGISTERS ---------------
// 8 keys/thread in VGPRs; no kv LDS (3 sweeps read registers). LDS ~17 KB ->
// 2 blocks/CU: block B's radix overlaps block A's barrier-bound sort.
// Candidate set + sort comparator identical to r15 -> bit-identical output.
__global__ __launch_bounds__(1024)
void k_halfsel(const uint32_t* __restrict__ key, uint64_t* __restrict__ cand)
{
    __shared__ uint64_t cv[2048];         // 16 KB
    __shared__ uint32_t hist[257];        // hist[256]=0 sentinel
    __shared__ uint32_t s_prefix, s_k, s_cnt;
    const int t = threadIdx.x;
    const int b = blockIdx.x;
    const int lane = t & 63;
    const uint32_t halfbase = (uint32_t)(b & 1) * HL;

    uint32_t rk[8];                       // keys 4t..4t+3, 4096+4t..4096+4t+3
    {
        const uint4* ks = (const uint4*)(key + (size_t)b * HL);
        uint4 a = ks[t], c = ks[t + 1024];
        rk[0] = a.x; rk[1] = a.y; rk[2] = a.z; rk[3] = a.w;
        rk[4] = c.x; rk[5] = c.y; rk[6] = c.z; rk[7] = c.w;
    }
    if (t == 0) { s_prefix = 0; s_k = TOPK; s_cnt = 0; }
    __syncthreads();

    // ---- 2 radix rounds: T16 = top-16 bits of the half's 1024th key ----
    #pragma unroll
    for (int round = 0; round < 2; ++round) {
        if (t < 257) hist[t] = 0;
        __syncthreads();
        const uint32_t pref = s_prefix;
        const uint32_t k = s_k;
        #pragma unroll
        for (int q = 0; q < 8; ++q) {
            uint32_t u = rk[q];
            if (round == 0) atomicAdd(&hist[u >> 24], 1u);
            else if ((u >> 24) == pref) atomicAdd(&hist[(u >> 16) & 255u], 1u);
        }
        __syncthreads();
        // wave-0 suffix scan over 256 bins (lane l owns bins 4l..4l+3)
        if (t < 64) {
            int l = t;
            uint32_t h0 = hist[4*l], h1 = hist[4*l+1], h2 = hist[4*l+2], h3 = hist[4*l+3];
            uint32_t s3 = h3, s2 = h2 + s3, s1 = h1 + s2, s0 = h0 + s1;
            uint32_t tot = s0, run = tot;
            #pragma unroll
            for (int off = 1; off < 64; off <<= 1) {
                int src = l + off < 64 ? l + off : 63;
                uint32_t o = __shfl(run, src, 64);
                if (l + off < 64) run += o;
            }
            uint32_t esuf = run - tot;
            hist[4*l]   = s0 + esuf; hist[4*l+1] = s1 + esuf;
            hist[4*l+2] = s2 + esuf; hist[4*l+3] = s3 + esuf;
        }
        __syncthreads();
        if (t < 256) {
            uint32_t st = hist[t], sn = hist[t + 1];
            if (st >= k && sn < k) {
                s_prefix = (pref << 8) | (uint32_t)t;
                s_k = k - sn;
            }
        }
        __syncthreads();
    }
    const uint32_t T = s_prefix << 16;

    // ---- collect candidates >= T (wave-aggregated, from registers) ----
    #pragma unroll
    for (int q = 0; q < 8; ++q) {
        bool qq = rk[q] >= T;
        unsigned long long m = __ballot(qq);
        uint32_t base = 0;
        if (lane == 0 && m)
            base = atomicAdd(&s_cnt, (uint32_t)__popcll(m));
        base = __shfl(base, 0);
        if (qq) {
            uint32_t idx = (q < 4) ? (4u * t + q) : (HL / 2 + 4u * t + (q - 4));
            uint32_t pos = base + (uint32_t)__popcll(m & ((1ULL << lane) - 1ULL));
            if (pos < 2048)
                cv[pos] = ((uint64_t)rk[q] << 32)
                        | (uint64_t)(uint32_t)(~(halfbase + idx));
        }
    }
    __syncthreads();
    const uint32_t mm = s_cnt < 2048u ? s_cnt : 2048u;
    for (int i = t; i < 2048; i += 1024)
        if ((uint32_t)i >= mm) cv[i] = 0ULL;
    __syncthreads();

    // ---- hybrid bitonic sort 2048 asc by (key,~idx) ----
    {   // Phase A: sizes 2..64 in registers via shfl
        uint64_t r0 = cv[t], r1 = cv[t + 1024];
        #pragma unroll
        for (int size = 2; size <= 64; size <<= 1) {
            bool up = ((t & size) == 0);
            #pragma unroll
            for (int s = size >> 1; s > 0; s >>= 1) {
                r0 = cex(r0, s, up, t);
                r1 = cex(r1, s, up, t);
            }
        }
        cv[t] = r0; cv[t + 1024] = r1;
    }
    // Phase B: sizes 128..2048 — strides >=64 via LDS, <=32 via shfl
    #pragma unroll
    for (int size = 128; size <= 2048; size <<= 1) {
        for (int s = size >> 1; s >= 64; s >>= 1) {
            __syncthreads();
            int i = ((t & ~(s - 1)) << 1) | (t & (s - 1));
            int j = i | s;
            uint64_t va = cv[i], vb = cv[j];
            bool up = ((i & size) == 0);
            if (up ? (va > vb) : (va < vb)) { cv[i] = vb; cv[j] = va; }
        }
        __syncthreads();
        {
            uint64_t a0 = cv[t], a1 = cv[t + 1024];
            bool up0, up1;
            if (size <= 512)      { up0 = ((t & size) == 0); up1 = up0; }
            else if (size == 1024){ up0 = true;  up1 = false; }
            else                  { up0 = true;  up1 = true;  }
            #pragma unroll
            for (int s = 32; s > 0; s >>= 1) {
                a0 = cex(a0, s, up0, t);
                a1 = cex(a1, s, up1, t);
            }
            cv[t] = a0; cv[t + 1024] = a1;
        }
        __syncthreads();
    }
    cand[(size_t)b * TOPK + t] = cv[2047 - t];   // half top-1024, desc
}

// ---------- Kernel 3: merge two half top-1024 lists (r15 exact) --------------
__global__ __launch_bounds__(1024)
void k_merge(const uint64_t* __restrict__ cand, int* __restrict__ idx_out)
{
    __shared__ uint64_t cv[2048];
    const int t = threadIdx.x;
    const int seg = blockIdx.x;
    cv[t]        = cand[(size_t)(seg * 2) * TOPK + t];
    cv[1024 + t] = cand[(size_t)(seg * 2 + 1) * TOPK + (1023 - t)];
    __syncthreads();
    for (int s = 1024; s >= 1; s >>= 1) {
        int i = ((t & ~(s - 1)) << 1) | (t & (s - 1));
        int j = i | s;
        uint64_t va = cv[i], vb = cv[j];
        if (va < vb) { cv[i] = vb; cv[j] = va; }   // descending
        __syncthreads();
    }
    idx_out[(size_t)seg * TOPK + t] = (int)(~(uint32_t)cv[t]);
}

// ---------------- Kernel 4: gather + K-split GEMM partials -------------------
// FT 64->32, grid (128,8) = 1024 blocks -> 4 blocks/CU (16 waves/CU): hides
// gather latency + barrier stalls. Per-output FMA sequence identical (same
// sub,kk order) -> bit-identical part. W still read exactly once (32 MB);
// gather redundancy x8 absorbed by L3 (distinct set 16 MB << 256 MB).
#define FT 32
#define KCI 32
#define NKC 128
#define KCHUNK 256   // = TOPK*CC / NKC

__global__ __launch_bounds__(256)
void k_fc(const float* __restrict__ x, const int* __restrict__ idx,
          const float* __restrict__ W, float* __restrict__ part, int L)
{
    __shared__ float flT[KCI][128];   // [k][b] 16 KB
    __shared__ float wT[KCI][FT];     // [k][f]  4 KB
    const int t = threadIdx.x;
    const int kc = blockIdx.x;
    const int fb = blockIdx.y * FT;
    const int tb = t >> 4, tf = t & 15;   // 16x16 grid: 8b x 2f per thread
    float acc[8][2];
    #pragma unroll
    for (int i = 0; i < 8; ++i) {
        acc[i][0] = 0.f; acc[i][1] = 0.f;
    }

    const int b_ld = t >> 1, half = t & 1;
    for (int sub = 0; sub < KCHUNK / KCI; ++sub) {
        const int kbase = kc * KCHUNK + sub * KCI;
        const int t_idx = kbase >> 5;    // KCI == CC: one topk position per sub
        {   // stage gathered x rows: flT[c][b]
            int row = idx[b_ld * TOPK + t_idx];
            row = row < 0 ? 0 : (row >= L ? L - 1 : row);
            const float* src = x + ((size_t)b_ld * L + row) * CC + half * 16;
            #pragma unroll
            for (int q = 0; q < 4; ++q) {
                float4 v = ((const float4*)src)[q];
                int c0 = half * 16 + q * 4;
                flT[c0 + 0][b_ld] = v.x; flT[c0 + 1][b_ld] = v.y;
                flT[c0 + 2][b_ld] = v.z; flT[c0 + 3][b_ld] = v.w;
            }
        }
        {   // stage W transposed: wT[k][f], 32 f x 32 k = 1024 floats
            int fl = t >> 3, u = t & 7;
            const float4 v = *(const float4*)(W + (size_t)(fb + fl) * (TOPK * CC) + kbase + u * 4);
            wT[u * 4 + 0][fl] = v.x; wT[u * 4 + 1][fl] = v.y;
            wT[u * 4 + 2][fl] = v.z; wT[u * 4 + 3][fl] = v.w;
        }
        __syncthreads();
        #pragma unroll
        for (int kk = 0; kk < KCI; ++kk) {
            float bb[8], ww[2];
            *(float4*)&bb[0] = *(const float4*)&flT[kk][tb * 8];
            *(float4*)&bb[4] = *(const float4*)&flT[kk][tb * 8 + 4];
            *(float2*)&ww[0] = *(const float2*)&wT[kk][tf * 2];
            #pragma unroll
            for (int i = 0; i < 8; ++i) {
                acc[i][0] = fmaf(bb[i], ww[0], acc[i][0]);
                acc[i][1] = fmaf(bb[i], ww[1], acc[i][1]);
            }
        }
        __syncthreads();
    }
    float* pbase = part + ((size_t)kc * 128) * 256 + fb + tf * 2;
    #pragma unroll
    for (int i = 0; i < 8; ++i) {
        float* dst = pbase + (size_t)(tb * 8 + i) * 256;
        ((float2*)dst)[0] = make_float2(acc[i][0], acc[i][1]);
    }
}

// ---------------- Kernel 5: reduce partials + bias + BN2 + L2 norm (r15 exact)
__global__ __launch_bounds__(256)
void k_post(const float* __restrict__ part, const float* __restrict__ b_fc,
            const float* __restrict__ g2, const float* __restrict__ be2,
            const float* __restrict__ rm2, const float* __restrict__ rv2,
            float* __restrict__ out)
{
    __shared__ float red[256];
    const int b = blockIdx.x, f = threadIdx.x;
    float s = 0.f;
    #pragma unroll 8
    for (int kc = 0; kc < NKC; ++kc)
        s += part[((size_t)kc * 128 + b) * 256 + f];
    s += b_fc[f];
    float o = (s - rm2[f]) * (g2[f] / sqrtf(rv2[f] + 1e-5f)) + be2[f];
    red[f] = o * o;
    __syncthreads();
    for (int st = 128; st > 0; st >>= 1) {
        if (f < st) red[f] += red[f + st];
        __syncthreads();
    }
    float nrm = fmaxf(sqrtf(red[0]), 1e-12f);
    out[(size_t)b * 256 + f] = o / nrm;
}

extern "C" void kernel_launch(void* const* d_in, const int* in_sizes, int n_in,
                              void* d_out, int out_size, void* d_ws, size_t ws_size,
                              hipStream_t stream)
{
    const float* x     = (const float*)d_in[0];
    const float* w_att = (const float*)d_in[2];
    const float* b_att = (const float*)d_in[3];
    const float* W_fc  = (const float*)d_in[8];
    const float* b_fc  = (const float*)d_in[9];
    const float* g2    = (const float*)d_in[10];
    const float* be2   = (const float*)d_in[11];
    const float* rm2   = (const float*)d_in[12];
    const float* rv2   = (const float*)d_in[13];

    const int N = in_sizes[0] / CC;   // 2097152
    const int B = in_sizes[1];        // 128
    const int L = N / B;              // 16384

    // workspace layout
    const size_t off_key  = 0;                                   // 8 MB
    const size_t off_cand = off_key + (size_t)N * 4;             // 2 MB
    const size_t off_idx  = off_cand + (size_t)2 * B * TOPK * 8; // 512 KB
    const size_t off_part = off_idx + (size_t)B * TOPK * 4;      // 16 MB

    uint8_t* ws = (uint8_t*)d_ws;
    uint32_t* key  = (uint32_t*)(ws + off_key);
    uint64_t* cand = (uint64_t*)(ws + off_cand);
    int* idx       = (int*)(ws + off_idx);
    float* part    = (float*)(ws + off_part);

    k_att<<<N / 256, 256, 0, stream>>>(x, w_att, b_att, key, N);
    k_halfsel<<<2 * B, 1024, 0, stream>>>(key, cand);
    k_merge<<<B, 1024, 0, stream>>>(cand, idx);
    dim3 g3(NKC, FC0 / FT);
    k_fc<<<g3, 256, 0, stream>>>(x, idx, W_fc, part, L);
    k_post<<<B, 256, 0, stream>>>(part, b_fc, g2, be2, rm2, rv2, (float*)d_out);
}

// Round 20
// 115.188 us; speedup vs baseline: 2.7930x; 1.0651x over previous
//
#include <hip/hip_runtime.h>
#include <stdint.h>

#define CC 32
#define TOPK 1024
#define FC0 256
#define HL 8192   // half-segment length

// compare-exchange via shfl_xor: partner lane = lane^s (s <= 32, same wave).
__device__ __forceinline__ uint64_t cex(uint64_t v, int s, bool up, int t)
{
    uint64_t o = (uint64_t)__shfl_xor((unsigned long long)v, s, 64);
    bool left = ((t & s) == 0);
    uint64_t mn = v < o ? v : o;
    uint64_t mx = v < o ? o : v;
    return (left == up) ? mn : mx;
}

// ------------- Kernel 1: f32 att keys (r15 exact; measured 38.7 us = BW floor)
__global__ __launch_bounds__(256)
void k_att(const float* __restrict__ x,
           const float* __restrict__ w_att, const float* __restrict__ b_att,
           uint32_t* __restrict__ key, int N)
{
    __shared__ float tile[256][CC + 1];
    const int t = threadIdx.x;
    const size_t base = (size_t)blockIdx.x * 256;
    const float4* xv = (const float4*)(x + base * CC);
    #pragma unroll
    for (int i = 0; i < 8; ++i) {
        int e = i * 256 + t;
        float4 v = xv[e];
        int r = e >> 3, c4 = (e & 7) * 4;
        tile[r][c4 + 0] = v.x; tile[r][c4 + 1] = v.y;
        tile[r][c4 + 2] = v.z; tile[r][c4 + 3] = v.w;
    }
    __syncthreads();
    float p[8];
    #pragma unroll
    for (int j = 0; j < 8; ++j) {
        float pj = __fmul_rn(tile[t][j], w_att[j]);
        pj = __fmaf_rn(tile[t][8 + j],  w_att[8 + j],  pj);
        pj = __fmaf_rn(tile[t][16 + j], w_att[16 + j], pj);
        pj = __fmaf_rn(tile[t][24 + j], w_att[24 + j], pj);
        p[j] = pj;
    }
    float q0 = __fadd_rn(p[0], p[1]);
    float q1 = __fadd_rn(p[2], p[3]);
    float q2 = __fadd_rn(p[4], p[5]);
    float q3 = __fadd_rn(p[6], p[7]);
    float dot = __fadd_rn(__fadd_rn(q0, q1), __fadd_rn(q2, q3));
    float v = __fadd_rn(dot, b_att[0]);
    uint32_t bits = __float_as_uint(v);
    key[base + t] = (bits & 0x80000000u) ? ~bits : (bits | 0x80000000u);
}

// ---------- Kernel 2: half-segment top-1024 (r15 exact; measured 21.0 us) ----
__global__ __launch_bounds__(1024)
void k_halfsel(const uint32_t* __restrict__ key, uint64_t* __restrict__ cand)
{
    __shared__ uint32_t kv[HL];           // 32 KB
    __shared__ uint64_t cv[2048];         // 16 KB
    __shared__ uint32_t hist[257];        // hist[256]=0 sentinel
    __shared__ uint32_t s_prefix, s_k, s_cnt;
    const int t = threadIdx.x;
    const int b = blockIdx.x;
    const int lane = t & 63;
    const uint32_t halfbase = (uint32_t)(b & 1) * HL;

    {   // vectorized load: 8192 keys = 2048 uint4
        const uint4* ks = (const uint4*)(key + (size_t)b * HL);
        uint4 a = ks[t], c = ks[t + 1024];
        *(uint4*)&kv[t * 4] = a;
        *(uint4*)&kv[(t + 1024) * 4] = c;
    }
    if (t == 0) { s_prefix = 0; s_k = TOPK; s_cnt = 0; }
    __syncthreads();

    #pragma unroll
    for (int round = 0; round < 2; ++round) {
        if (t < 257) hist[t] = 0;
        __syncthreads();
        const uint32_t pref = s_prefix;
        const uint32_t k = s_k;
        for (int i = t; i < HL; i += 1024) {
            uint32_t u = kv[i];
            if (round == 0) atomicAdd(&hist[u >> 24], 1u);
            else if ((u >> 24) == pref) atomicAdd(&hist[(u >> 16) & 255u], 1u);
        }
        __syncthreads();
        if (t < 64) {
            int l = t;
            uint32_t h0 = hist[4*l], h1 = hist[4*l+1], h2 = hist[4*l+2], h3 = hist[4*l+3];
            uint32_t s3 = h3, s2 = h2 + s3, s1 = h1 + s2, s0 = h0 + s1;
            uint32_t tot = s0, run = tot;
            #pragma unroll
            for (int off = 1; off < 64; off <<= 1) {
                int src = l + off < 64 ? l + off : 63;
                uint32_t o = __shfl(run, src, 64);
                if (l + off < 64) run += o;
            }
            uint32_t esuf = run - tot;
            hist[4*l]   = s0 + esuf; hist[4*l+1] = s1 + esuf;
            hist[4*l+2] = s2 + esuf; hist[4*l+3] = s3 + esuf;
        }
        __syncthreads();
        if (t < 256) {
            uint32_t st = hist[t], sn = hist[t + 1];
            if (st >= k && sn < k) {
                s_prefix = (pref << 8) | (uint32_t)t;
                s_k = k - sn;
            }
        }
        __syncthreads();
    }
    const uint32_t T = s_prefix << 16;

    for (int i = t; i < HL; i += 1024) {
        bool q = kv[i] >= T;
        unsigned long long m = __ballot(q);
        uint32_t base = 0;
        if (lane == 0 && m)
            base = atomicAdd(&s_cnt, (uint32_t)__popcll(m));
        base = __shfl(base, 0);
        if (q) {
            uint32_t pos = base + (uint32_t)__popcll(m & ((1ULL << lane) - 1ULL));
            if (pos < 2048)
                cv[pos] = ((uint64_t)kv[i] << 32)
                        | (uint64_t)(uint32_t)(~(halfbase + (uint32_t)i));
        }
    }
    __syncthreads();
    const uint32_t mm = s_cnt < 2048u ? s_cnt : 2048u;
    for (int i = t; i < 2048; i += 1024)
        if ((uint32_t)i >= mm) cv[i] = 0ULL;
    __syncthreads();

    {   // Phase A: sizes 2..64 in registers via shfl
        uint64_t r0 = cv[t], r1 = cv[t + 1024];
        #pragma unroll
        for (int size = 2; size <= 64; size <<= 1) {
            bool up = ((t & size) == 0);
            #pragma unroll
            for (int s = size >> 1; s > 0; s >>= 1) {
                r0 = cex(r0, s, up, t);
                r1 = cex(r1, s, up, t);
            }
        }
        cv[t] = r0; cv[t + 1024] = r1;
    }
    #pragma unroll
    for (int size = 128; size <= 2048; size <<= 1) {
        for (int s = size >> 1; s >= 64; s >>= 1) {
            __syncthreads();
            int i = ((t & ~(s - 1)) << 1) | (t & (s - 1));
            int j = i | s;
            uint64_t va = cv[i], vb = cv[j];
            bool up = ((i & size) == 0);
            if (up ? (va > vb) : (va < vb)) { cv[i] = vb; cv[j] = va; }
        }
        __syncthreads();
        {
            uint64_t a0 = cv[t], a1 = cv[t + 1024];
            bool up0, up1;
            if (size <= 512)      { up0 = ((t & size) == 0); up1 = up0; }
            else if (size == 1024){ up0 = true;  up1 = false; }
            else                  { up0 = true;  up1 = true;  }
            #pragma unroll
            for (int s = 32; s > 0; s >>= 1) {
                a0 = cex(a0, s, up0, t);
                a1 = cex(a1, s, up1, t);
            }
            cv[t] = a0; cv[t + 1024] = a1;
        }
        __syncthreads();
    }
    cand[(size_t)b * TOPK + t] = cv[2047 - t];   // half top-1024, desc
}

// ---------- Kernel 3: merge two half top-1024 lists (r15 exact) --------------
__global__ __launch_bounds__(1024)
void k_merge(const uint64_t* __restrict__ cand, int* __restrict__ idx_out)
{
    __shared__ uint64_t cv[2048];
    const int t = threadIdx.x;
    const int seg = blockIdx.x;
    cv[t]        = cand[(size_t)(seg * 2) * TOPK + t];
    cv[1024 + t] = cand[(size_t)(seg * 2 + 1) * TOPK + (1023 - t)];
    __syncthreads();
    for (int s = 1024; s >= 1; s >>= 1) {
        int i = ((t & ~(s - 1)) << 1) | (t & (s - 1));
        int j = i | s;
        uint64_t va = cv[i], vb = cv[j];
        if (va < vb) { cv[i] = vb; cv[j] = va; }   // descending
        __syncthreads();
    }
    idx_out[(size_t)seg * TOPK + t] = (int)(~(uint32_t)cv[t]);
}

// ---------------- Kernel 4: gather + K-split GEMM partials (r15 exact) -------
#define FT 64
#define KCI 32
#define NKC 128
#define KCHUNK 256   // = TOPK*CC / NKC

__global__ __launch_bounds__(256)
void k_fc(const float* __restrict__ x, const int* __restrict__ idx,
          const float* __restrict__ W, float* __restrict__ part, int L)
{
    __shared__ float flT[KCI][128];   // [k][b] 16 KB
    __shared__ float wT[KCI][FT];     // [k][f]  8 KB
    const int t = threadIdx.x;
    const int kc = blockIdx.x;
    const int fb = blockIdx.y * FT;
    const int tb = t >> 4, tf = t & 15;   // 16x16 grid: 8b x 4f per thread
    float acc[8][4];
    #pragma unroll
    for (int i = 0; i < 8; ++i)
        #pragma unroll
        for (int j = 0; j < 4; ++j) acc[i][j] = 0.f;

    const int b_ld = t >> 1, half = t & 1;
    for (int sub = 0; sub < KCHUNK / KCI; ++sub) {
        const int kbase = kc * KCHUNK + sub * KCI;
        const int t_idx = kbase >> 5;    // KCI == CC: one topk position per sub
        {   // stage gathered x rows: flT[c][b]
            int row = idx[b_ld * TOPK + t_idx];
            row = row < 0 ? 0 : (row >= L ? L - 1 : row);
            const float* src = x + ((size_t)b_ld * L + row) * CC + half * 16;
            #pragma unroll
            for (int q = 0; q < 4; ++q) {
                float4 v = ((const float4*)src)[q];
                int c0 = half * 16 + q * 4;
                flT[c0 + 0][b_ld] = v.x; flT[c0 + 1][b_ld] = v.y;
                flT[c0 + 2][b_ld] = v.z; flT[c0 + 3][b_ld] = v.w;
            }
        }
        {   // stage W transposed: wT[k][f], 64 f x 32 k
            #pragma unroll
            for (int i2 = 0; i2 < 2; ++i2) {
                int e = t + i2 * 256;
                int fl = e >> 3, u = e & 7;
                const float4 v = *(const float4*)(W + (size_t)(fb + fl) * (TOPK * CC) + kbase + u * 4);
                wT[u * 4 + 0][fl] = v.x; wT[u * 4 + 1][fl] = v.y;
                wT[u * 4 + 2][fl] = v.z; wT[u * 4 + 3][fl] = v.w;
            }
        }
        __syncthreads();
        #pragma unroll
        for (int kk = 0; kk < KCI; ++kk) {
            float bb[8], ww[4];
            *(float4*)&bb[0] = *(const float4*)&flT[kk][tb * 8];
            *(float4*)&bb[4] = *(const float4*)&flT[kk][tb * 8 + 4];
            *(float4*)&ww[0] = *(const float4*)&wT[kk][tf * 4];
            #pragma unroll
            for (int i = 0; i < 8; ++i)
                #pragma unroll
                for (int j = 0; j < 4; ++j)
                    acc[i][j] = fmaf(bb[i], ww[j], acc[i][j]);
        }
        __syncthreads();
    }
    float* pbase = part + ((size_t)kc * 128) * 256 + fb + tf * 4;
    #pragma unroll
    for (int i = 0; i < 8; ++i) {
        float* dst = pbase + (size_t)(tb * 8 + i) * 256;
        ((float4*)dst)[0] = make_float4(acc[i][0], acc[i][1], acc[i][2], acc[i][3]);
    }
}

// ---------------- Kernel 5: reduce partials + bias + BN2 + L2 norm (r15 exact)
__global__ __launch_bounds__(256)
void k_post(const float* __restrict__ part, const float* __restrict__ b_fc,
            const float* __restrict__ g2, const float* __restrict__ be2,
            const float* __restrict__ rm2, const float* __restrict__ rv2,
            float* __restrict__ out)
{
    __shared__ float red[256];
    const int b = blockIdx.x, f = threadIdx.x;
    float s = 0.f;
    #pragma unroll 8
    for (int kc = 0; kc < NKC; ++kc)
        s += part[((size_t)kc * 128 + b) * 256 + f];
    s += b_fc[f];
    float o = (s - rm2[f]) * (g2[f] / sqrtf(rv2[f] + 1e-5f)) + be2[f];
    red[f] = o * o;
    __syncthreads();
    for (int st = 128; st > 0; st >>= 1) {
        if (f < st) red[f] += red[f + st];
        __syncthreads();
    }
    float nrm = fmaxf(sqrtf(red[0]), 1e-12f);
    out[(size_t)b * 256 + f] = o / nrm;
}

extern "C" void kernel_launch(void* const* d_in, const int* in_sizes, int n_in,
                              void* d_out, int out_size, void* d_ws, size_t ws_size,
                              hipStream_t stream)
{
    const float* x     = (const float*)d_in[0];
    const float* w_att = (const float*)d_in[2];
    const float* b_att = (const float*)d_in[3];
    const float* W_fc  = (const float*)d_in[8];
    const float* b_fc  = (const float*)d_in[9];
    const float* g2    = (const float*)d_in[10];
    const float* be2   = (const float*)d_in[11];
    const float* rm2   = (const float*)d_in[12];
    const float* rv2   = (const float*)d_in[13];

    const int N = in_sizes[0] / CC;   // 2097152
    const int B = in_sizes[1];        // 128
    const int L = N / B;              // 16384

    // workspace layout
    const size_t off_key  = 0;                                   // 8 MB
    const size_t off_cand = off_key + (size_t)N * 4;             // 2 MB
    const size_t off_idx  = off_cand + (size_t)2 * B * TOPK * 8; // 512 KB
    const size_t off_part = off_idx + (size_t)B * TOPK * 4;      // 16 MB

    uint8_t* ws = (uint8_t*)d_ws;
    uint32_t* key  = (uint32_t*)(ws + off_key);
    uint64_t* cand = (uint64_t*)(ws + off_cand);
    int* idx       = (int*)(ws + off_idx);
    float* part    = (float*)(ws + off_part);

    k_att<<<N / 256, 256, 0, stream>>>(x, w_att, b_att, key, N);
    k_halfsel<<<2 * B, 1024, 0, stream>>>(key, cand);
    k_merge<<<B, 1024, 0, stream>>>(cand, idx);
    dim3 g3(NKC, FC0 / FT);
    k_fc<<<g3, 256, 0, stream>>>(x, idx, W_fc, part, L);
    k_post<<<B, 256, 0, stream>>>(part, b_fc, g2, be2, rm2, rv2, (float*)d_out);
}

// Round 21
// 105.182 us; speedup vs baseline: 3.0587x; 1.0951x over previous
//
#include <hip/hip_runtime.h>
#include <stdint.h>

#define CC 32
#define TOPK 1024
#define FC0 256
#define HL 8192   // half-segment length

typedef __attribute__((ext_vector_type(8))) short bf16x8;
typedef __attribute__((ext_vector_type(4))) float f32x4;

// f32 -> bf16 round-to-nearest-even
__device__ __forceinline__ ushort f2bf(float f) {
    uint32_t u = __float_as_uint(f);
    uint32_t r = u + 0x7FFFu + ((u >> 16) & 1u);
    return (ushort)(r >> 16);
}

// compare-exchange via shfl_xor: partner lane = lane^s (s <= 32, same wave).
__device__ __forceinline__ uint64_t cex(uint64_t v, int s, bool up, int t)
{
    uint64_t o = (uint64_t)__shfl_xor((unsigned long long)v, s, 64);
    bool left = ((t & s) == 0);
    uint64_t mn = v < o ? v : o;
    uint64_t mx = v < o ? o : v;
    return (left == up) ? mn : mx;
}

// ------------- Kernel 1: f32 att keys (r15 exact; measured 38.7 us = BW floor)
__global__ __launch_bounds__(256)
void k_att(const float* __restrict__ x,
           const float* __restrict__ w_att, const float* __restrict__ b_att,
           uint32_t* __restrict__ key, int N)
{
    __shared__ float tile[256][CC + 1];
    const int t = threadIdx.x;
    const size_t base = (size_t)blockIdx.x * 256;
    const float4* xv = (const float4*)(x + base * CC);
    #pragma unroll
    for (int i = 0; i < 8; ++i) {
        int e = i * 256 + t;
        float4 v = xv[e];
        int r = e >> 3, c4 = (e & 7) * 4;
        tile[r][c4 + 0] = v.x; tile[r][c4 + 1] = v.y;
        tile[r][c4 + 2] = v.z; tile[r][c4 + 3] = v.w;
    }
    __syncthreads();
    float p[8];
    #pragma unroll
    for (int j = 0; j < 8; ++j) {
        float pj = __fmul_rn(tile[t][j], w_att[j]);
        pj = __fmaf_rn(tile[t][8 + j],  w_att[8 + j],  pj);
        pj = __fmaf_rn(tile[t][16 + j], w_att[16 + j], pj);
        pj = __fmaf_rn(tile[t][24 + j], w_att[24 + j], pj);
        p[j] = pj;
    }
    float q0 = __fadd_rn(p[0], p[1]);
    float q1 = __fadd_rn(p[2], p[3]);
    float q2 = __fadd_rn(p[4], p[5]);
    float q3 = __fadd_rn(p[6], p[7]);
    float dot = __fadd_rn(__fadd_rn(q0, q1), __fadd_rn(q2, q3));
    float v = __fadd_rn(dot, b_att[0]);
    uint32_t bits = __float_as_uint(v);
    key[base + t] = (bits & 0x80000000u) ? ~bits : (bits | 0x80000000u);
}

// ---------- Kernel 2: half-segment top-1024 (r15 exact; measured 21.0 us) ----
__global__ __launch_bounds__(1024)
void k_halfsel(const uint32_t* __restrict__ key, uint64_t* __restrict__ cand)
{
    __shared__ uint32_t kv[HL];           // 32 KB
    __shared__ uint64_t cv[2048];         // 16 KB
    __shared__ uint32_t hist[257];        // hist[256]=0 sentinel
    __shared__ uint32_t s_prefix, s_k, s_cnt;
    const int t = threadIdx.x;
    const int b = blockIdx.x;
    const int lane = t & 63;
    const uint32_t halfbase = (uint32_t)(b & 1) * HL;

    {   // vectorized load: 8192 keys = 2048 uint4
        const uint4* ks = (const uint4*)(key + (size_t)b * HL);
        uint4 a = ks[t], c = ks[t + 1024];
        *(uint4*)&kv[t * 4] = a;
        *(uint4*)&kv[(t + 1024) * 4] = c;
    }
    if (t == 0) { s_prefix = 0; s_k = TOPK; s_cnt = 0; }
    __syncthreads();

    #pragma unroll
    for (int round = 0; round < 2; ++round) {
        if (t < 257) hist[t] = 0;
        __syncthreads();
        const uint32_t pref = s_prefix;
        const uint32_t k = s_k;
        for (int i = t; i < HL; i += 1024) {
            uint32_t u = kv[i];
            if (round == 0) atomicAdd(&hist[u >> 24], 1u);
            else if ((u >> 24) == pref) atomicAdd(&hist[(u >> 16) & 255u], 1u);
        }
        __syncthreads();
        if (t < 64) {
            int l = t;
            uint32_t h0 = hist[4*l], h1 = hist[4*l+1], h2 = hist[4*l+2], h3 = hist[4*l+3];
            uint32_t s3 = h3, s2 = h2 + s3, s1 = h1 + s2, s0 = h0 + s1;
            uint32_t tot = s0, run = tot;
            #pragma unroll
            for (int off = 1; off < 64; off <<= 1) {
                int src = l + off < 64 ? l + off : 63;
                uint32_t o = __shfl(run, src, 64);
                if (l + off < 64) run += o;
            }
            uint32_t esuf = run - tot;
            hist[4*l]   = s0 + esuf; hist[4*l+1] = s1 + esuf;
            hist[4*l+2] = s2 + esuf; hist[4*l+3] = s3 + esuf;
        }
        __syncthreads();
        if (t < 256) {
            uint32_t st = hist[t], sn = hist[t + 1];
            if (st >= k && sn < k) {
                s_prefix = (pref << 8) | (uint32_t)t;
                s_k = k - sn;
            }
        }
        __syncthreads();
    }
    const uint32_t T = s_prefix << 16;

    for (int i = t; i < HL; i += 1024) {
        bool q = kv[i] >= T;
        unsigned long long m = __ballot(q);
        uint32_t base = 0;
        if (lane == 0 && m)
            base = atomicAdd(&s_cnt, (uint32_t)__popcll(m));
        base = __shfl(base, 0);
        if (q) {
            uint32_t pos = base + (uint32_t)__popcll(m & ((1ULL << lane) - 1ULL));
            if (pos < 2048)
                cv[pos] = ((uint64_t)kv[i] << 32)
                        | (uint64_t)(uint32_t)(~(halfbase + (uint32_t)i));
        }
    }
    __syncthreads();
    const uint32_t mm = s_cnt < 2048u ? s_cnt : 2048u;
    for (int i = t; i < 2048; i += 1024)
        if ((uint32_t)i >= mm) cv[i] = 0ULL;
    __syncthreads();

    {   // Phase A: sizes 2..64 in registers via shfl
        uint64_t r0 = cv[t], r1 = cv[t + 1024];
        #pragma unroll
        for (int size = 2; size <= 64; size <<= 1) {
            bool up = ((t & size) == 0);
            #pragma unroll
            for (int s = size >> 1; s > 0; s >>= 1) {
                r0 = cex(r0, s, up, t);
                r1 = cex(r1, s, up, t);
            }
        }
        cv[t] = r0; cv[t + 1024] = r1;
    }
    #pragma unroll
    for (int size = 128; size <= 2048; size <<= 1) {
        for (int s = size >> 1; s >= 64; s >>= 1) {
            __syncthreads();
            int i = ((t & ~(s - 1)) << 1) | (t & (s - 1));
            int j = i | s;
            uint64_t va = cv[i], vb = cv[j];
            bool up = ((i & size) == 0);
            if (up ? (va > vb) : (va < vb)) { cv[i] = vb; cv[j] = va; }
        }
        __syncthreads();
        {
            uint64_t a0 = cv[t], a1 = cv[t + 1024];
            bool up0, up1;
            if (size <= 512)      { up0 = ((t & size) == 0); up1 = up0; }
            else if (size == 1024){ up0 = true;  up1 = false; }
            else                  { up0 = true;  up1 = true;  }
            #pragma unroll
            for (int s = 32; s > 0; s >>= 1) {
                a0 = cex(a0, s, up0, t);
                a1 = cex(a1, s, up1, t);
            }
            cv[t] = a0; cv[t + 1024] = a1;
        }
        __syncthreads();
    }
    cand[(size_t)b * TOPK + t] = cv[2047 - t];   // half top-1024, desc
}

// ---------- Kernel 3: merge two half top-1024 lists (r15 exact) --------------
__global__ __launch_bounds__(1024)
void k_merge(const uint64_t* __restrict__ cand, int* __restrict__ idx_out)
{
    __shared__ uint64_t cv[2048];
    const int t = threadIdx.x;
    const int seg = blockIdx.x;
    cv[t]        = cand[(size_t)(seg * 2) * TOPK + t];
    cv[1024 + t] = cand[(size_t)(seg * 2 + 1) * TOPK + (1023 - t)];
    __syncthreads();
    for (int s = 1024; s >= 1; s >>= 1) {
        int i = ((t & ~(s - 1)) << 1) | (t & (s - 1));
        int j = i | s;
        uint64_t va = cv[i], vb = cv[j];
        if (va < vb) { cv[i] = vb; cv[j] = va; }   // descending
        __syncthreads();
    }
    idx_out[(size_t)seg * TOPK + t] = (int)(~(uint32_t)cv[t]);
}

// ---------------- Kernel 4: gather + K-split GEMM partials via bf16 MFMA -----
// Block (kc, fb): 4 waves; wave w owns f-tile ni=w (16 f). A = gathered x rows
// (128 b x 32 k) bf16 in LDS [128][40] (80B stride: aligned b128 frags, 2-way
// banks = free). B-frags direct from global W (16 rows x 128B dense per wave),
// reused across 8 M-tiles in registers. mfma_f32_16x16x32_bf16; D mapping per
// HW-verified m89: row=(lane>>4)*4+reg, col=lane&15. f32 accumulate -> part.
#define NKC 128
#define KCHUNK 256   // = TOPK*CC / NKC

__global__ __launch_bounds__(256)
void k_fc(const float* __restrict__ x, const int* __restrict__ idx,
          const float* __restrict__ W, float* __restrict__ part, int L)
{
    __shared__ ushort flA[128][40];   // 10 KB, bf16 gathered rows
    const int t = threadIdx.x;
    const int w = t >> 6;             // wave id -> ni
    const int l = t & 63;
    const int l15 = l & 15;
    const int lq = l >> 4;            // k-quadrant (8 k each)
    const int kc = blockIdx.x;
    const int fb = blockIdx.y * 64;

    f32x4 acc[8];
    #pragma unroll
    for (int mi = 0; mi < 8; ++mi) acc[mi] = (f32x4){0.f, 0.f, 0.f, 0.f};

    const int b_ld = t >> 1, half = t & 1;
    const float* Wrow = W + (size_t)(fb + w * 16 + l15) * (TOPK * CC);

    for (int sub = 0; sub < 8; ++sub) {
        const int kbase = kc * KCHUNK + sub * 32;
        const int t_idx = kbase >> 5;
        {   // stage A: row b_ld, 16 f32 -> bf16 (thread covers half*16..+16)
            int row = idx[b_ld * TOPK + t_idx];
            row = row < 0 ? 0 : (row >= L ? L - 1 : row);
            const float4* src = (const float4*)(x + ((size_t)b_ld * L + row) * CC + half * 16);
            ushort* dst = &flA[b_ld][half * 16];
            #pragma unroll
            for (int q = 0; q < 4; ++q) {
                float4 v = src[q];
                *(uint32_t*)(dst + q * 4)     = (uint32_t)f2bf(v.x) | ((uint32_t)f2bf(v.y) << 16);
                *(uint32_t*)(dst + q * 4 + 2) = (uint32_t)f2bf(v.z) | ((uint32_t)f2bf(v.w) << 16);
            }
        }
        // B-frag: lane (l15,lq) = W[fb+w*16+l15][kbase + lq*8 .. +8]
        bf16x8 bfrag;
        {
            const float* wp = Wrow + kbase + lq * 8;
            float4 w0 = ((const float4*)wp)[0];
            float4 w1 = ((const float4*)wp)[1];
            bfrag[0] = (short)f2bf(w0.x); bfrag[1] = (short)f2bf(w0.y);
            bfrag[2] = (short)f2bf(w0.z); bfrag[3] = (short)f2bf(w0.w);
            bfrag[4] = (short)f2bf(w1.x); bfrag[5] = (short)f2bf(w1.y);
            bfrag[6] = (short)f2bf(w1.z); bfrag[7] = (short)f2bf(w1.w);
        }
        __syncthreads();
        #pragma unroll
        for (int mi = 0; mi < 8; ++mi) {
            bf16x8 afrag = *(const bf16x8*)&flA[mi * 16 + l15][lq * 8];
            acc[mi] = __builtin_amdgcn_mfma_f32_16x16x32_bf16(afrag, bfrag, acc[mi], 0, 0, 0);
        }
        __syncthreads();
    }
    // D write: part[(kc*128 + brow)*256 + fb + w*16 + l15]
    float* pb = part + ((size_t)kc * 128) * 256 + fb + w * 16 + l15;
    #pragma unroll
    for (int mi = 0; mi < 8; ++mi) {
        const int brow0 = mi * 16 + lq * 4;
        #pragma unroll
        for (int r = 0; r < 4; ++r)
            pb[(size_t)(brow0 + r) * 256] = acc[mi][r];
    }
}

// ---------------- Kernel 5: reduce partials + bias + BN2 + L2 norm (r15 exact)
__global__ __launch_bounds__(256)
void k_post(const float* __restrict__ part, const float* __restrict__ b_fc,
            const float* __restrict__ g2, const float* __restrict__ be2,
            const float* __restrict__ rm2, const float* __restrict__ rv2,
            float* __restrict__ out)
{
    __shared__ float red[256];
    const int b = blockIdx.x, f = threadIdx.x;
    float s = 0.f;
    #pragma unroll 8
    for (int kc = 0; kc < NKC; ++kc)
        s += part[((size_t)kc * 128 + b) * 256 + f];
    s += b_fc[f];
    float o = (s - rm2[f]) * (g2[f] / sqrtf(rv2[f] + 1e-5f)) + be2[f];
    red[f] = o * o;
    __syncthreads();
    for (int st = 128; st > 0; st >>= 1) {
        if (f < st) red[f] += red[f + st];
        __syncthreads();
    }
    float nrm = fmaxf(sqrtf(red[0]), 1e-12f);
    out[(size_t)b * 256 + f] = o / nrm;
}

extern "C" void kernel_launch(void* const* d_in, const int* in_sizes, int n_in,
                              void* d_out, int out_size, void* d_ws, size_t ws_size,
                              hipStream_t stream)
{
    const float* x     = (const float*)d_in[0];
    const float* w_att = (const float*)d_in[2];
    const float* b_att = (const float*)d_in[3];
    const float* W_fc  = (const float*)d_in[8];
    const float* b_fc  = (const float*)d_in[9];
    const float* g2    = (const float*)d_in[10];
    const float* be2   = (const float*)d_in[11];
    const float* rm2   = (const float*)d_in[12];
    const float* rv2   = (const float*)d_in[13];

    const int N = in_sizes[0] / CC;   // 2097152
    const int B = in_sizes[1];        // 128
    const int L = N / B;              // 16384

    // workspace layout
    const size_t off_key  = 0;                                   // 8 MB
    const size_t off_cand = off_key + (size_t)N * 4;             // 2 MB
    const size_t off_idx  = off_cand + (size_t)2 * B * TOPK * 8; // 512 KB
    const size_t off_part = off_idx + (size_t)B * TOPK * 4;      // 16 MB

    uint8_t* ws = (uint8_t*)d_ws;
    uint32_t* key  = (uint32_t*)(ws + off_key);
    uint64_t* cand = (uint64_t*)(ws + off_cand);
    int* idx       = (int*)(ws + off_idx);
    float* part    = (float*)(ws + off_part);

    k_att<<<N / 256, 256, 0, stream>>>(x, w_att, b_att, key, N);
    k_halfsel<<<2 * B, 1024, 0, stream>>>(key, cand);
    k_merge<<<B, 1024, 0, stream>>>(cand, idx);
    dim3 g3(NKC, FC0 / 64);
    k_fc<<<g3, 256, 0, stream>>>(x, idx, W_fc, part, L);
    k_post<<<B, 256, 0, stream>>>(part, b_fc, g2, be2, rm2, rv2, (float*)d_out);
}